// Round 9
// baseline (213.788 us; speedup 1.0000x reference)
//
#include <hip/hip_runtime.h>
#include <hip/hip_bf16.h>

// ---------------------------------------------------------------------------
// GCN 3-layer, N=50000, E=800000, D=64, fp32 in/out.
// R9: aggregation split into two feature-half passes. The bf16 gather table
// (6.4 MB) missed the 4 MiB per-XCD L2 (R5: ~90 MB FETCH/layer fp32). Each
// pass now gathers from a 3.2 MB plane (features 0-31 / 32-63) that fits
// L2 -> compulsory fills only, gathers become L2 hits. GEMM epilogue writes
// plane-major bf16 directly. MFMA gemm from R8 (45us fp32 GEMM -> ~5us);
// bucket adjacency + XCD-partitioned fill from R3/R4.
// ---------------------------------------------------------------------------

#define CAP 64
#define EDGE_CHUNK 1024

typedef __attribute__((ext_vector_type(8))) short bf16x8;
typedef __attribute__((ext_vector_type(4))) float f32x4;

// --- pack two fp32 -> bf16x2 (RNE) ----------------------------------------
__device__ inline unsigned pack_bf16(float a, float b) {
    union { float f; unsigned i; } ua, ub;
    ua.f = a; ub.f = b;
    unsigned x = (ua.i + 0x7fffu + ((ua.i >> 16) & 1u)) >> 16;
    unsigned y = (ub.i + 0x7fffu + ((ub.i >> 16) & 1u)) >> 16;
    return x | (y << 16);
}
__device__ inline unsigned short to_bf16(float a) {
    union { float f; unsigned i; } u; u.f = a;
    return (unsigned short)((u.i + 0x7fffu + ((u.i >> 16) & 1u)) >> 16);
}
// --- accumulate bf16x2 (packed uint) into two floats ----------------------
__device__ inline void acc_bf16x2(unsigned u, float& a, float& b) {
    union { unsigned i; float f; } lo, hi;
    lo.i = u << 16;
    hi.i = u & 0xffff0000u;
    a += lo.f; b += hi.f;
}

// --- fused count+place: slot = atomicAdd(cnt), XCD-partitioned by dst -----
__global__ void fill_kernel(const int* __restrict__ src, const int* __restrict__ dst,
                            int* __restrict__ cnt, int* __restrict__ adj,
                            int E, int npc) {
    int cls = blockIdx.x & 7;          // -> XCD (round-robin heuristic)
    int base = (blockIdx.x >> 3) * EDGE_CHUNK;
    int end = min(base + EDGE_CHUNK, E);
    int lo = cls * npc, hi = lo + npc;
    for (int e = base + threadIdx.x; e < end; e += blockDim.x) {
        int d = dst[e];
        if (d >= lo && d < hi) {
            int p = atomicAdd(&cnt[d], 1);
            adj[(size_t)d * CAP + p] = src[e];
        }
    }
}

// --- g(bf16, plane-major) = dinv ⊙ (in @ W) via MFMA; 64 rows/block -------
// plane p holds features [32p, 32p+32) : g[p*N*32 + node*32 + (c&31)]
__global__ __launch_bounds__(256) void gemm_kernel(const float* __restrict__ in,
                                                   const float* __restrict__ W,
                                                   const int* __restrict__ cnt,
                                                   unsigned short* __restrict__ g, int n) {
    __shared__ unsigned short Wb[512 * 8];  // B-frags: 8 (s,c) x 64 lanes x 8 bf16
    int t = threadIdx.x;

    // ---- stage W into B-fragment order (bf16) ----
#pragma unroll
    for (int e0 = 0; e0 < 2; e0++) {
        int e = t + e0 * 256;          // frag index 0..511
        int sc = e >> 6;               // s*4 + c
        int l  = e & 63;               // target lane
        int s = sc >> 2, c = sc & 3;
        int nn = c * 16 + (l & 15);
        int kb = s * 32 + (l >> 4) * 8;
        const float* wp = &W[(size_t)kb * 64 + nn];
        unsigned q0 = pack_bf16(wp[0 * 64], wp[1 * 64]);
        unsigned q1 = pack_bf16(wp[2 * 64], wp[3 * 64]);
        unsigned q2 = pack_bf16(wp[4 * 64], wp[5 * 64]);
        unsigned q3 = pack_bf16(wp[6 * 64], wp[7 * 64]);
        *(uint4*)&Wb[e * 8] = make_uint4(q0, q1, q2, q3);
    }

    int wv = t >> 6;
    int lane = t & 63;
    int quad = lane >> 4;
    int m16 = lane & 15;

    // ---- A fragments: row m16 of this wave's 16-row slab, k per quad ----
    int rowA = blockIdx.x * 64 + wv * 16 + m16;
    union { bf16x8 v; uint4 u; } a0, a1;
    {
        float4 f0 = make_float4(0, 0, 0, 0), f1 = f0, f2 = f0, f3 = f0;
        if (rowA < n) {
            const float* rp = &in[(size_t)rowA * 64];
            f0 = *(const float4*)&rp[quad * 8];
            f1 = *(const float4*)&rp[quad * 8 + 4];
            f2 = *(const float4*)&rp[32 + quad * 8];
            f3 = *(const float4*)&rp[32 + quad * 8 + 4];
        }
        a0.u = make_uint4(pack_bf16(f0.x, f0.y), pack_bf16(f0.z, f0.w),
                          pack_bf16(f1.x, f1.y), pack_bf16(f1.z, f1.w));
        a1.u = make_uint4(pack_bf16(f2.x, f2.y), pack_bf16(f2.z, f2.w),
                          pack_bf16(f3.x, f3.y), pack_bf16(f3.z, f3.w));
    }
    __syncthreads();

    // ---- 8 MFMAs: 4 col-tiles x 2 k-steps ----
    f32x4 acc[4];
#pragma unroll
    for (int c = 0; c < 4; c++) {
        bf16x8 b0 = *(const bf16x8*)&Wb[((size_t)(0 * 4 + c) * 64 + lane) * 8];
        bf16x8 b1 = *(const bf16x8*)&Wb[((size_t)(1 * 4 + c) * 64 + lane) * 8];
        f32x4 z = {0.f, 0.f, 0.f, 0.f};
        z = __builtin_amdgcn_mfma_f32_16x16x32_bf16(a0.v, b0, z, 0, 0, 0);
        z = __builtin_amdgcn_mfma_f32_16x16x32_bf16(a1.v, b1, z, 0, 0, 0);
        acc[c] = z;
    }

    // ---- epilogue: scale by dinv[row], store bf16 plane-major ----
    int rowbase = blockIdx.x * 64 + wv * 16 + quad * 4;
    float dv[4];
#pragma unroll
    for (int r = 0; r < 4; r++) {
        int row = rowbase + r;
        dv[r] = (row < n) ? rsqrtf((float)(cnt[row] + 1)) : 0.f;
    }
    size_t pstride = (size_t)n * 32;
#pragma unroll
    for (int c = 0; c < 4; c++) {
        unsigned short* gp = g + (size_t)(c >> 1) * pstride;
        int colp = (c & 1) * 16 + m16;
#pragma unroll
        for (int r = 0; r < 4; r++) {
            int row = rowbase + r;
            if (row < n)
                gp[(size_t)row * 32 + colp] = to_bf16(acc[c][r] * dv[r]);
        }
    }
}

// --- agg half-pass: 8 lanes/node (uint2 = 4 bf16), 32 nodes/block ---------
// gplane: 3.2 MB plane (L2-resident). co = feature offset (0 or 32).
// out[i, co..co+31] = dinv*(gp[i] + sum_nbr gp[j]) + bias (+relu+res MODE 0)
template <int MODE>
__global__ __launch_bounds__(256) void agg_kernel(const unsigned short* __restrict__ gplane,
                                                  const int* __restrict__ cnt,
                                                  const int* __restrict__ adj,
                                                  const float* __restrict__ bias,  // +co
                                                  const float* __restrict__ res,
                                                  float* __restrict__ out,
                                                  int co, int n) {
    int t = threadIdx.x;
    int lg = t & 7;                    // lane within 8-lane node group
    int i = blockIdx.x * 32 + (t >> 3);
    if (i >= n) return;
    int deg = cnt[i];
    const int* lst = adj + (size_t)i * CAP;
    const int c4 = lg * 4;             // bf16 feature offset within plane
    float ax = 0.f, ay = 0.f, az = 0.f, aw = 0.f;
    {   // self loop
        uint2 v = *(const uint2*)&gplane[(size_t)i * 32 + c4];
        acc_bf16x2(v.x, ax, ay);
        acc_bf16x2(v.y, az, aw);
    }
    int k = 0;
    for (; k + 8 <= deg; k += 8) {     // 8 independent row gathers in flight
        int j0 = lst[k], j1 = lst[k + 1], j2 = lst[k + 2], j3 = lst[k + 3];
        int j4 = lst[k + 4], j5 = lst[k + 5], j6 = lst[k + 6], j7 = lst[k + 7];
        uint2 v0 = *(const uint2*)&gplane[(size_t)j0 * 32 + c4];
        uint2 v1 = *(const uint2*)&gplane[(size_t)j1 * 32 + c4];
        uint2 v2 = *(const uint2*)&gplane[(size_t)j2 * 32 + c4];
        uint2 v3 = *(const uint2*)&gplane[(size_t)j3 * 32 + c4];
        uint2 v4 = *(const uint2*)&gplane[(size_t)j4 * 32 + c4];
        uint2 v5 = *(const uint2*)&gplane[(size_t)j5 * 32 + c4];
        uint2 v6 = *(const uint2*)&gplane[(size_t)j6 * 32 + c4];
        uint2 v7 = *(const uint2*)&gplane[(size_t)j7 * 32 + c4];
        acc_bf16x2(v0.x, ax, ay); acc_bf16x2(v0.y, az, aw);
        acc_bf16x2(v1.x, ax, ay); acc_bf16x2(v1.y, az, aw);
        acc_bf16x2(v2.x, ax, ay); acc_bf16x2(v2.y, az, aw);
        acc_bf16x2(v3.x, ax, ay); acc_bf16x2(v3.y, az, aw);
        acc_bf16x2(v4.x, ax, ay); acc_bf16x2(v4.y, az, aw);
        acc_bf16x2(v5.x, ax, ay); acc_bf16x2(v5.y, az, aw);
        acc_bf16x2(v6.x, ax, ay); acc_bf16x2(v6.y, az, aw);
        acc_bf16x2(v7.x, ax, ay); acc_bf16x2(v7.y, az, aw);
    }
    if (k + 4 <= deg) {
        int j0 = lst[k], j1 = lst[k + 1], j2 = lst[k + 2], j3 = lst[k + 3];
        uint2 v0 = *(const uint2*)&gplane[(size_t)j0 * 32 + c4];
        uint2 v1 = *(const uint2*)&gplane[(size_t)j1 * 32 + c4];
        uint2 v2 = *(const uint2*)&gplane[(size_t)j2 * 32 + c4];
        uint2 v3 = *(const uint2*)&gplane[(size_t)j3 * 32 + c4];
        acc_bf16x2(v0.x, ax, ay); acc_bf16x2(v0.y, az, aw);
        acc_bf16x2(v1.x, ax, ay); acc_bf16x2(v1.y, az, aw);
        acc_bf16x2(v2.x, ax, ay); acc_bf16x2(v2.y, az, aw);
        acc_bf16x2(v3.x, ax, ay); acc_bf16x2(v3.y, az, aw);
        k += 4;
    }
    for (; k < deg; k++) {
        uint2 v = *(const uint2*)&gplane[(size_t)lst[k] * 32 + c4];
        acc_bf16x2(v.x, ax, ay);
        acc_bf16x2(v.y, az, aw);
    }
    float dv = rsqrtf((float)(deg + 1));
    float4 bb = *(const float4*)&bias[c4];
    float4 v;
    v.x = dv * ax + bb.x;
    v.y = dv * ay + bb.y;
    v.z = dv * az + bb.z;
    v.w = dv * aw + bb.w;
    size_t rowoff = (size_t)i * 64 + co + c4;
    if (MODE == 0) {
        float4 r = *(const float4*)&res[rowoff];
        v.x = fmaxf(v.x, 0.f) + r.x;
        v.y = fmaxf(v.y, 0.f) + r.y;
        v.z = fmaxf(v.z, 0.f) + r.z;
        v.w = fmaxf(v.w, 0.f) + r.w;
    }
    *(float4*)&out[rowoff] = v;
}

extern "C" void kernel_launch(void* const* d_in, const int* in_sizes, int n_in,
                              void* d_out, int out_size, void* d_ws, size_t ws_size,
                              hipStream_t stream) {
    const float* x  = (const float*)d_in[0];
    const int*   ei = (const int*)d_in[1];
    const float* W1 = (const float*)d_in[2];
    const float* b1 = (const float*)d_in[3];
    const float* W2 = (const float*)d_in[4];
    const float* b2 = (const float*)d_in[5];
    const float* W3 = (const float*)d_in[6];
    const float* b3 = (const float*)d_in[7];
    float* out = (float*)d_out;

    const int N = in_sizes[0] / 64;
    const int E = in_sizes[1] / 2;
    const int* src = ei;
    const int* dst = ei + E;
    const int npc = (N + 7) / 8;
    const int nEdgeChunks = (E + EDGE_CHUNK - 1) / EDGE_CHUNK;

    // workspace layout
    char* p = (char*)d_ws;
    int*            cnt = (int*)p;            p += ((N + 63) / 64) * 64 * 4;
    int*            adj = (int*)p;            p += ((size_t)N + 1) * CAP * 4;
    unsigned short* g   = (unsigned short*)p; p += (size_t)N * 64 * 2;  // 2 planes
    float*          h   = (float*)p;          p += (size_t)N * 64 * 4;
    const size_t pstride = (size_t)N * 32;
    unsigned short* g0 = g;
    unsigned short* g1 = g + pstride;

    const int aggBlocks  = (N + 31) / 32;
    const int gemmBlocks = (N + 63) / 64;

    // --- bucket adjacency build (ws re-poisoned every call) ---
    hipMemsetAsync(cnt, 0, (size_t)N * 4, stream);
    fill_kernel<<<nEdgeChunks * 8, 256, 0, stream>>>(src, dst, cnt, adj, E, npc);

    // --- layer 1: h = relu(agg(dinv⊙(x@W1))) + x ---
    gemm_kernel<<<gemmBlocks, 256, 0, stream>>>(x, W1, cnt, g, N);
    agg_kernel<0><<<aggBlocks, 256, 0, stream>>>(g0, cnt, adj, b1,      x, h, 0,  N);
    agg_kernel<0><<<aggBlocks, 256, 0, stream>>>(g1, cnt, adj, b1 + 32, x, h, 32, N);

    // --- layer 2: h = relu(agg(dinv⊙(h@W2))) + h ---
    gemm_kernel<<<gemmBlocks, 256, 0, stream>>>(h, W2, cnt, g, N);
    agg_kernel<0><<<aggBlocks, 256, 0, stream>>>(g0, cnt, adj, b2,      h, h, 0,  N);
    agg_kernel<0><<<aggBlocks, 256, 0, stream>>>(g1, cnt, adj, b2 + 32, h, h, 32, N);

    // --- layer 3: out = agg(dinv⊙(h@W3)) ---
    gemm_kernel<<<gemmBlocks, 256, 0, stream>>>(h, W3, cnt, g, N);
    agg_kernel<1><<<aggBlocks, 256, 0, stream>>>(g0, cnt, adj, b3,      nullptr, out, 0,  N);
    agg_kernel<1><<<aggBlocks, 256, 0, stream>>>(g1, cnt, adj, b3 + 32, nullptr, out, 32, N);
}